// Round 3
// baseline (465.041 us; speedup 1.0000x reference)
//
#include <hip/hip_runtime.h>
#include <stdint.h>

// Problem constants: B=4096, D=256, N=8192, P=4096
// sigma = sqrt(1/(0.07*ln2)); vectors normalized * sigma so MFMA dot is the
// exp2 argument directly: exp(sim/T) = exp2(dot). sigma^2 = 20.6099253
#define K_SIGMA 4.5398156f
#define LN2F    0.6931471805599453f

typedef __attribute__((ext_vector_type(8)))  short short8;
typedef __attribute__((ext_vector_type(16))) float f32x16;

__device__ __forceinline__ float bf2f(uint16_t u) {
  union { uint32_t i; float f; } v; v.i = ((uint32_t)u) << 16; return v.f;
}
__device__ __forceinline__ uint16_t f2bf(float f) {
  union { float f; uint32_t i; } v; v.f = f;
  uint32_t b = v.i;
  b += 0x7FFF + ((b >> 16) & 1);   // RNE
  return (uint16_t)(b >> 16);
}

// ---------------------------------------------------------------------------
// 1) Normalize rows -> bf16*sigma; zero rowsum accumulators + counters + out.
//    One wave per row.
// ---------------------------------------------------------------------------
__global__ __launch_bounds__(256) void normalize_kernel(
    const float* __restrict__ z1, const float* __restrict__ z2,
    const float* __restrict__ emb,
    uint16_t* __restrict__ zb, uint16_t* __restrict__ eb,
    float* __restrict__ zero_region, float* __restrict__ out)
{
  const int gtid = blockIdx.x * 256 + threadIdx.x;
  if (gtid < 12352) zero_region[gtid] = 0.0f;  // rs_z[8192]+rs_s[4096]+counters
  if (gtid == 0) { out[0] = 0.0f; out[1] = 0.0f; }

  const int w = threadIdx.x >> 6, lane = threadIdx.x & 63;
  const int row = blockIdx.x * 4 + w;  // 0..16383
  const float* src;
  uint16_t* dst;
  if (row < 4096)      { src = z1  + row * 256;          dst = zb + row * 256; }
  else if (row < 8192) { src = z2  + (row - 4096) * 256; dst = zb + row * 256; }
  else                 { src = emb + (row - 8192) * 256; dst = eb + (row - 8192) * 256; }
  float4 v = *reinterpret_cast<const float4*>(src + lane * 4);
  float ss = v.x * v.x + v.y * v.y + v.z * v.z + v.w * v.w;
#pragma unroll
  for (int m = 1; m < 64; m <<= 1) ss += __shfl_xor(ss, m);
  float inv = K_SIGMA / fmaxf(sqrtf(ss), 1e-12f);
  ushort4 o;
  o.x = f2bf(v.x * inv); o.y = f2bf(v.y * inv);
  o.z = f2bf(v.z * inv); o.w = f2bf(v.w * inv);
  *reinterpret_cast<ushort4*>(dst + lane * 4) = o;
}

// ---------------------------------------------------------------------------
// 2) Fused sweep v3: BM=256 (wave owns 64 rows = 2x 32-row tiles, afrag in
//    regs: 128 VGPR), mfma_32x32x16, BN=32 LDS tile (acc = 1x f32x16 per
//    tile = 32 VGPR total), double-buffered 2-phase prefetch.
//    bid < 1024: simclr (32 rb x 32 cc); else spatial (16 rb x 32 cc).
//    Each block sweeps 256 cols = 8 tiles of 32.
//    Last block per row-group (counter) computes the per-row losses and
//    atomically accumulates the two means into out[] (finalize+reduce fused).
// ---------------------------------------------------------------------------
__global__ __launch_bounds__(256, 2) void sweep_kernel(
    const uint16_t* __restrict__ zb, const uint16_t* __restrict__ eb,
    const int* __restrict__ anchor, const int* __restrict__ neighbor,
    float* __restrict__ rs_z, float* __restrict__ rs_s,
    int* __restrict__ counters, float* __restrict__ out)
{
  __shared__ __align__(16) uint16_t lds[2][32 * 256];   // 2 x 16 KiB
  __shared__ int   isLast;
  __shared__ float bsum[4];

  const int bid  = blockIdx.x;
  const int tid  = threadIdx.x;
  const int w    = tid >> 6;
  const int lane = tid & 63;
  const int ln   = lane & 31;
  const int hi   = lane >> 5;

  const bool spatial = (bid >= 1024);
  const int sub = spatial ? (bid - 1024) : bid;
  const int rb  = sub >> 5;
  const int cc  = sub & 31;
  const uint16_t* __restrict__ Amat = spatial ? eb : zb;
  const uint16_t* __restrict__ Bmat = spatial ? eb : zb;
  float* __restrict__ rs = spatial ? rs_s : rs_z;

  const int row_base = rb * 256 + w * 64;

  // A fragments (32x32x16): row = lane&31, k = ks*16 + hi*8 + j
  short8 afrag[2][16];
#pragma unroll
  for (int t = 0; t < 2; ++t) {
    int r  = row_base + t * 32 + ln;
    int sr = spatial ? anchor[r] : r;
    const uint16_t* ap = Amat + sr * 256 + hi * 8;
#pragma unroll
    for (int ks = 0; ks < 16; ++ks)
      afrag[t][ks] = *reinterpret_cast<const short8*>(ap + ks * 16);
  }

  float rsacc0[16], rsacc1[16];
#pragma unroll
  for (int r = 0; r < 16; ++r) { rsacc0[r] = 0.0f; rsacc1[r] = 0.0f; }

  const int cbase = cc * 256;
  const int srow   = (((tid >> 6) & 3) + ((tid & 63) >> 5) * 0);  // placeholder (unused)

  // stage one 32-col tile: 16 gload_lds instrs (4/wave), each covers 2 rows.
  // LDS linear (row, chunk); global source pre-inverse-swizzled: kchunk ^= row&15
  auto STAGE = [&](int buf, int step) {
    const int col0 = cbase + step * 32;
#pragma unroll
    for (int i = 0; i < 4; ++i) {
      const int row   = (i * 4 + w) * 2 + hi;   // 0..31
      const int chunk = ln;                      // 0..31 (16B units)
      const uint16_t* src = Bmat + (col0 + row) * 256 + ((chunk ^ (row & 15)) << 3);
      uint16_t* dst = &lds[buf][row * 256 + chunk * 8];  // linear in lane x16B
      __builtin_amdgcn_global_load_lds(
          (const __attribute__((address_space(1))) void*)src,
          (__attribute__((address_space(3))) void*)dst, 16, 0, 0);
    }
  };

  STAGE(0, 0);
  __syncthreads();
  int cur = 0;

  for (int step = 0; step < 8; ++step) {
    if (step < 7) STAGE(cur ^ 1, step + 1);   // prefetch overlaps compute

    f32x16 acc0, acc1;
#pragma unroll
    for (int r = 0; r < 16; ++r) { acc0[r] = 0.0f; acc1[r] = 0.0f; }

#pragma unroll
    for (int ks = 0; ks < 16; ++ks) {
      const int ch = (ks * 2 + hi) ^ (ln & 15);      // 4-bit swizzled 16B chunk
      short8 bfrag = *reinterpret_cast<const short8*>(&lds[cur][ln * 256 + ch * 8]);
      acc0 = __builtin_amdgcn_mfma_f32_32x32x16_bf16(afrag[0][ks], bfrag, acc0, 0, 0, 0);
      acc1 = __builtin_amdgcn_mfma_f32_32x32x16_bf16(afrag[1][ks], bfrag, acc1, 0, 0, 0);
    }

#pragma unroll
    for (int r = 0; r < 16; ++r) {
      rsacc0[r] += exp2f(acc0[r]);
      rsacc1[r] += exp2f(acc1[r]);
    }

    __syncthreads();               // current tile's ds_reads done + prefetch landed
    cur ^= 1;
  }

  // C/D layout (32x32): col = lane&31, row = (reg&3) + 8*(reg>>2) + 4*hi.
  // Reduce across the 32 column-lanes, then atomicAdd per row.
#pragma unroll
  for (int t = 0; t < 2; ++t)
#pragma unroll
    for (int r = 0; r < 16; ++r) {
      float v = t ? rsacc1[r] : rsacc0[r];
      v += __shfl_xor(v, 1);
      v += __shfl_xor(v, 2);
      v += __shfl_xor(v, 4);
      v += __shfl_xor(v, 8);
      v += __shfl_xor(v, 16);
      if (ln == 0) {
        int row = row_base + t * 32 + (r & 3) + 8 * (r >> 2) + 4 * hi;
        atomicAdd(&rs[row], v);
      }
    }

  // ---- last-block-per-row-group: fused finalize + reduce ----
  __syncthreads();                 // all waves' atomics issued & drained
  if (tid == 0) {
    __threadfence();
    int old = atomicAdd(&counters[(spatial ? 32 : 0) + rb], 1);
    isLast = (old == 31);
  }
  __syncthreads();
  if (!isLast) return;
  __threadfence();

  float lsum = 0.0f;
  for (int i = 0; i < 64; ++i) {
    const int rl = i * 4 + w;            // 0..255 within this row group
    const uint16_t *pa, *pb;
    float rsv;
    bool same = false;
    if (!spatial) {
      int row  = rb * 256 + rl;
      int pair = (row < 4096) ? row + 4096 : row - 4096;
      pa = zb + row * 256;
      pb = zb + pair * 256;
      rsv = __hip_atomic_load(&rs_z[row], __ATOMIC_RELAXED, __HIP_MEMORY_SCOPE_AGENT);
    } else {
      int idx = rb * 256 + rl;
      int ai = anchor[idx], ni = neighbor[idx];
      same = (ai == ni);
      pa = eb + ai * 256;
      pb = eb + ni * 256;
      rsv = __hip_atomic_load(&rs_s[idx], __ATOMIC_RELAXED, __HIP_MEMORY_SCOPE_AGENT);
    }
    ushort4 ua = *reinterpret_cast<const ushort4*>(pa + lane * 4);
    ushort4 ub = *reinterpret_cast<const ushort4*>(pb + lane * 4);
    float a0 = bf2f(ua.x), a1 = bf2f(ua.y), a2 = bf2f(ua.z), a3 = bf2f(ua.w);
    float b0 = bf2f(ub.x), b1 = bf2f(ub.y), b2 = bf2f(ub.z), b3 = bf2f(ub.w);
    float dd = a0 * a0 + a1 * a1 + a2 * a2 + a3 * a3;  // self-dot (scaled)
    float dn = a0 * b0 + a1 * b1 + a2 * b2 + a3 * b3;  // pair/neighbor dot
#pragma unroll
    for (int m = 1; m < 64; m <<= 1) {
      dd += __shfl_xor(dd, m);
      dn += __shfl_xor(dn, m);
    }
    if (lane == 0) {
      float S = spatial ? (rsv - exp2f(dd) + (same ? exp2f(dn) : 0.0f))
                        : (rsv - exp2f(dd));
      lsum += logf(S) - dn * LN2F;
    }
  }
  if (lane == 0) bsum[w] = lsum;
  __syncthreads();
  if (tid == 0)
    atomicAdd(&out[spatial ? 1 : 0],
              (bsum[0] + bsum[1] + bsum[2] + bsum[3]) *
                  (spatial ? (1.0f / 4096.0f) : (1.0f / 8192.0f)));
}

// ---------------------------------------------------------------------------
extern "C" void kernel_launch(void* const* d_in, const int* in_sizes, int n_in,
                              void* d_out, int out_size, void* d_ws, size_t ws_size,
                              hipStream_t stream) {
  const float* z1      = (const float*)d_in[0];
  const float* z2      = (const float*)d_in[1];
  const float* emb     = (const float*)d_in[2];
  const int*   anchor  = (const int*)d_in[3];
  const int*   neighbor= (const int*)d_in[4];
  float* out = (float*)d_out;

  float* ws      = (float*)d_ws;
  float* rs_z    = ws;                        // 8192 f32
  float* rs_s    = ws + 8192;                 // 4096 f32
  int*   counters= (int*)(ws + 12288);        // 48 ints (zeroed as floats)
  uint16_t* zb   = (uint16_t*)(ws + 12352);   // 8192*256 bf16 (4 MiB)
  uint16_t* eb   = zb + 8192 * 256;           // 8192*256 bf16 (4 MiB)

  normalize_kernel<<<4096, 256, 0, stream>>>(z1, z2, emb, zb, eb, ws, out);
  sweep_kernel<<<1536, 256, 0, stream>>>(zb, eb, anchor, neighbor,
                                         rs_z, rs_s, counters, out);
}

// Round 4
// 183.436 us; speedup vs baseline: 2.5352x; 2.5352x over previous
//
#include <hip/hip_runtime.h>
#include <stdint.h>

// Problem constants: B=4096, D=256, N=8192, P=4096
// sigma = sqrt(1/(0.07*ln2)); vectors normalized * sigma so the MFMA dot is
// the exp2 argument directly: exp(sim/T) = exp2(dot). sigma^2 = 20.6099253
#define K_SIGMA 4.5398156f
#define LN2F    0.6931471805599453f

typedef __attribute__((ext_vector_type(4))) float f32x4;

// ---- OCP e4m3fn encode (RNE; inputs bounded |x| <= ~4.6, no sat needed) ----
__device__ __forceinline__ uint32_t f2e4m3(float x) {
  union { float f; uint32_t u; } c; c.f = x;
  uint32_t s = (c.u >> 24) & 0x80u;
  uint32_t a = c.u & 0x7fffffffu;
  if (a >= 0x3C800000u) {                       // |x| >= 2^-6 : normal
    uint32_t r = a + 0x0007FFFFu + ((a >> 20) & 1u);  // RNE to 3 mantissa bits
    uint32_t e = (r >> 23) - 120u;
    uint32_t m = (r >> 20) & 7u;
    return s | (e << 3) | m;
  }
  union { uint32_t u; float f; } av; av.u = a;  // subnormal: units of 2^-9
  int q = (int)rintf(av.f * 512.0f);            // 0..8, RNE
  if (q == 8) return s | 0x08u;                 // rounds up to 2^-6
  return s | (uint32_t)q;
}

// ---- e4m3fn decode (must match HW MFMA interpretation) ----
__device__ __forceinline__ float e4m3f(uint32_t b) {
  uint32_t e = (b >> 3) & 15u, m = b & 7u;
  if (e) {
    union { uint32_t u; float f; } c;
    c.u = ((b & 0x80u) << 24) | ((e + 120u) << 23) | (m << 20);
    return c.f;
  }
  float sub = (float)m * 0.001953125f;          // m * 2^-9
  return (b & 0x80u) ? -sub : sub;
}

// ---------------------------------------------------------------------------
// 1) Normalize rows -> fp8 e4m3 * sigma; zero rowsums+counters+out.
//    One wave per row (16384 rows).
// ---------------------------------------------------------------------------
__global__ __launch_bounds__(256) void normalize_kernel(
    const float* __restrict__ z1, const float* __restrict__ z2,
    const float* __restrict__ emb,
    uint8_t* __restrict__ zb, uint8_t* __restrict__ eb,
    float* __restrict__ zero_region, float* __restrict__ out)
{
  const int gtid = blockIdx.x * 256 + threadIdx.x;
  if (gtid < 12384) zero_region[gtid] = 0.0f;   // rs_z + rs_s + counters
  if (gtid == 0) { out[0] = 0.0f; out[1] = 0.0f; }

  const int w = threadIdx.x >> 6, lane = threadIdx.x & 63;
  const int row = blockIdx.x * 4 + w;           // 0..16383
  const float* src;
  uint8_t* dst;
  if (row < 4096)      { src = z1  + row * 256;          dst = zb + row * 256; }
  else if (row < 8192) { src = z2  + (row - 4096) * 256; dst = zb + row * 256; }
  else                 { src = emb + (row - 8192) * 256; dst = eb + (row - 8192) * 256; }
  float4 v = *reinterpret_cast<const float4*>(src + lane * 4);
  float ss = v.x * v.x + v.y * v.y + v.z * v.z + v.w * v.w;
#pragma unroll
  for (int m = 1; m < 64; m <<= 1) ss += __shfl_xor(ss, m);
  float inv = K_SIGMA / fmaxf(sqrtf(ss), 1e-12f);
  uint32_t packed = f2e4m3(v.x * inv)
                  | (f2e4m3(v.y * inv) << 8)
                  | (f2e4m3(v.z * inv) << 16)
                  | (f2e4m3(v.w * inv) << 24);
  *reinterpret_cast<uint32_t*>(dst + lane * 4) = packed;
}

// ---------------------------------------------------------------------------
// 2) Fused sweep v4 (fp8): BM=128 (wave owns 32 rows = 2x 16-row tiles),
//    mfma_f32_16x16x32_fp8_fp8, BN=64 LDS col-tile (16 KiB), double-buffered
//    prefetch-before-compute, K=256 in A-registers (only 32 VGPR in fp8).
//    LDS layout [64 cols][32 x 8B chunks], XOR-swizzled: chunk' = chunk ^
//    (col&30) (bit0 preserved so global_load_lds 16B source stays contiguous).
//    bid < 512: simclr (64 rb x 8 cc); else spatial (32 rb x 8 cc).
//    Each block sweeps 1024 cols = 16 tiles of 64.
//    Last block per row-group computes per-row losses + mean (fused tail).
// ---------------------------------------------------------------------------
__global__ __launch_bounds__(256) void sweep_kernel(
    const uint8_t* __restrict__ zb, const uint8_t* __restrict__ eb,
    const int* __restrict__ anchor, const int* __restrict__ neighbor,
    float* __restrict__ rs_z, float* __restrict__ rs_s,
    int* __restrict__ counters, float* __restrict__ out)
{
  __shared__ __align__(16) uint8_t lds[2][64 * 256];   // 2 x 16 KiB
  __shared__ int   isLast;
  __shared__ float bsum[4];

  const int bid  = blockIdx.x;
  const int tid  = threadIdx.x;
  const int w    = tid >> 6;
  const int lane = tid & 63;
  const int lo4  = lane & 15;
  const int hi4  = lane >> 4;        // 0..3

  const bool spatial = (bid >= 512);
  const int sub = spatial ? (bid - 512) : bid;
  const int rb  = sub >> 3;          // simclr 0..63, spatial 0..31
  const int cc  = sub & 7;
  const uint8_t* __restrict__ Amat = spatial ? eb : zb;
  const uint8_t* __restrict__ Bmat = spatial ? eb : zb;
  float* __restrict__ rs = spatial ? rs_s : rs_z;

  const int row_base = rb * 128 + w * 32;

  // A fragments: row = lane&15, k = ks*32 + hi4*8 + byte. 2 tiles x 8 ks.
  long afrag[2][8];
#pragma unroll
  for (int t = 0; t < 2; ++t) {
    int r  = row_base + t * 16 + lo4;
    int sr = spatial ? anchor[r] : r;
    const uint8_t* ap = Amat + sr * 256 + hi4 * 8;
#pragma unroll
    for (int ks = 0; ks < 8; ++ks)
      afrag[t][ks] = *reinterpret_cast<const long*>(ap + ks * 32);
  }

  float rsacc[2][4];
#pragma unroll
  for (int t = 0; t < 2; ++t)
#pragma unroll
    for (int r = 0; r < 4; ++r) rsacc[t][r] = 0.0f;

  const int cbase = cc * 1024;

  // Stage one 64-col tile (16 KiB) via 4 global_load_lds per wave.
  // dst is tid-linear (wave-uniform base + lane*16); source 16B chunk is
  // pre-inverse-swizzled: srcch = ch16 ^ ((col_s & 30) >> 1).
  auto STAGE = [&](int buf, int step) {
    const int col0 = cbase + step * 64;
#pragma unroll
    for (int i = 0; i < 4; ++i) {
      const int col_s = i * 16 + w * 4 + hi4;       // 0..63
      const int ch16  = lo4;                        // 16B chunk in row
      const int srcch = ch16 ^ ((col_s & 30) >> 1);
      const uint8_t* src = Bmat + (col0 + col_s) * 256 + (srcch << 4);
      uint8_t* dst = &lds[buf][col_s * 256 + ch16 * 16];
      __builtin_amdgcn_global_load_lds(
          (const __attribute__((address_space(1))) void*)src,
          (__attribute__((address_space(3))) void*)dst, 16, 0, 0);
    }
  };

  STAGE(0, 0);
  __syncthreads();                  // vmcnt(0) drain: tile 0 staged
  int cur = 0;

  for (int step = 0; step < 16; ++step) {
    if (step < 15) STAGE(cur ^ 1, step + 1);   // prefetch overlaps compute

    f32x4 acc[2][4];
#pragma unroll
    for (int t = 0; t < 2; ++t)
#pragma unroll
      for (int ct = 0; ct < 4; ++ct) {
        f32x4 z = {0.0f, 0.0f, 0.0f, 0.0f};
        acc[t][ct] = z;
      }

#pragma unroll
    for (int ks = 0; ks < 8; ++ks) {
#pragma unroll
      for (int ct = 0; ct < 4; ++ct) {
        const int col = ct * 16 + lo4;
        const int cp  = (ks * 4 + hi4) ^ (col & 30);   // swizzled 8B chunk
        long bfrag = *reinterpret_cast<const long*>(&lds[cur][col * 256 + cp * 8]);
        acc[0][ct] = __builtin_amdgcn_mfma_f32_16x16x32_fp8_fp8(afrag[0][ks], bfrag, acc[0][ct], 0, 0, 0);
        acc[1][ct] = __builtin_amdgcn_mfma_f32_16x16x32_fp8_fp8(afrag[1][ks], bfrag, acc[1][ct], 0, 0, 0);
      }
    }

    // epilogue: exp2 + per-lane partial rowsums
#pragma unroll
    for (int t = 0; t < 2; ++t)
#pragma unroll
      for (int r = 0; r < 4; ++r)
        rsacc[t][r] += exp2f(acc[t][0][r]) + exp2f(acc[t][1][r])
                     + exp2f(acc[t][2][r]) + exp2f(acc[t][3][r]);

    __syncthreads();               // ds_reads done + prefetch landed
    cur ^= 1;
  }

  // C/D 16x16 layout: col = lane&15, row = hi4*4 + r. Reduce over 16 cols.
#pragma unroll
  for (int t = 0; t < 2; ++t)
#pragma unroll
    for (int r = 0; r < 4; ++r) {
      float v = rsacc[t][r];
      v += __shfl_xor(v, 1);
      v += __shfl_xor(v, 2);
      v += __shfl_xor(v, 4);
      v += __shfl_xor(v, 8);
      if (lo4 == 0) {
        int row = row_base + t * 16 + hi4 * 4 + r;
        atomicAdd(&rs[row], v);
      }
    }

  // ---- last-block-per-row-group: fused finalize + reduce ----
  __syncthreads();
  if (tid == 0) {
    __threadfence();
    int old = atomicAdd(&counters[(spatial ? 64 : 0) + rb], 1);
    isLast = (old == 7);
  }
  __syncthreads();
  if (!isLast) return;
  __threadfence();

  float lsum = 0.0f;
  for (int i = 0; i < 32; ++i) {
    const int rl = i * 4 + w;            // 0..127 within this row group
    const uint8_t *pa, *pb;
    float rsv;
    bool same = false;
    if (!spatial) {
      int row  = rb * 128 + rl;
      int pair = (row < 4096) ? row + 4096 : row - 4096;
      pa = zb + row * 256;
      pb = zb + pair * 256;
      rsv = __hip_atomic_load(&rs_z[row], __ATOMIC_RELAXED, __HIP_MEMORY_SCOPE_AGENT);
    } else {
      int idx = rb * 128 + rl;
      int ai = anchor[idx], ni = neighbor[idx];
      same = (ai == ni);
      pa = eb + ai * 256;
      pb = eb + ni * 256;
      rsv = __hip_atomic_load(&rs_s[idx], __ATOMIC_RELAXED, __HIP_MEMORY_SCOPE_AGENT);
    }
    uint32_t ua = *reinterpret_cast<const uint32_t*>(pa + lane * 4);
    uint32_t ub = *reinterpret_cast<const uint32_t*>(pb + lane * 4);
    float dd = 0.0f, dn = 0.0f;
#pragma unroll
    for (int j = 0; j < 4; ++j) {
      float av = e4m3f((ua >> (8 * j)) & 0xFFu);
      float bv = e4m3f((ub >> (8 * j)) & 0xFFu);
      dd += av * av;
      dn += av * bv;
    }
#pragma unroll
    for (int m = 1; m < 64; m <<= 1) {
      dd += __shfl_xor(dd, m);
      dn += __shfl_xor(dn, m);
    }
    if (lane == 0) {
      float S = spatial ? (rsv - exp2f(dd) + (same ? exp2f(dn) : 0.0f))
                        : (rsv - exp2f(dd));
      lsum += logf(S) - dn * LN2F;
    }
  }
  if (lane == 0) bsum[w] = lsum;
  __syncthreads();
  if (tid == 0)
    atomicAdd(&out[spatial ? 1 : 0],
              (bsum[0] + bsum[1] + bsum[2] + bsum[3]) *
                  (spatial ? (1.0f / 4096.0f) : (1.0f / 8192.0f)));
}

// ---------------------------------------------------------------------------
extern "C" void kernel_launch(void* const* d_in, const int* in_sizes, int n_in,
                              void* d_out, int out_size, void* d_ws, size_t ws_size,
                              hipStream_t stream) {
  const float* z1      = (const float*)d_in[0];
  const float* z2      = (const float*)d_in[1];
  const float* emb     = (const float*)d_in[2];
  const int*   anchor  = (const int*)d_in[3];
  const int*   neighbor= (const int*)d_in[4];
  float* out = (float*)d_out;

  float* ws      = (float*)d_ws;
  float* rs_z    = ws;                        // 8192 f32
  float* rs_s    = ws + 8192;                 // 4096 f32
  int*   counters= (int*)(ws + 12288);        // 96 ints (zeroed as floats)
  uint8_t* zb    = (uint8_t*)(ws + 12384);    // 8192*256 fp8 (2 MiB)
  uint8_t* eb    = zb + 8192 * 256;           // 8192*256 fp8 (2 MiB)

  normalize_kernel<<<4096, 256, 0, stream>>>(z1, z2, emb, zb, eb, ws, out);
  sweep_kernel<<<768, 256, 0, stream>>>(zb, eb, anchor, neighbor,
                                        rs_z, rs_s, counters, out);
}